// Round 10
// baseline (276.388 us; speedup 1.0000x reference)
//
#include <hip/hip_runtime.h>
#include <stdint.h>

// out[M,N] = x[M,K] @ dequant(W_q_packed)[K,N] + bias[N]
// M=N=K=4096, 4-bit nibbles packed 8/int32 along K, GROUP=128.
// R15: B bypasses LDS. Diagnosis: R12 (126us) is LDS-port+MFMA dead heat
// (reads 62 + writes 20 vs MFMA 58us); R14 proved occupancy doesn't help
// when LDS-bound. Fix: dequant writes W in FRAGMENT-MAJOR layout (16B cell
// = one lane's B-operand: wf[(nf*128+t)*64+lane], lane=fc*16+fr <-> col=
// nf*16+fr, k=t*32+fc*8..+8); gemm loads B-frags L2->regs via coalesced
// dwordx4 (panel XCD-L2-resident; 2x wm-redundancy = 1GB L2 ~30us on idle
// VMEM pipe; 1-tile lead covers L2 latency). LDS = A only: 3-ring x 16KB,
// traffic 130->80 KB/tile (2.6GB ~50us) < MFMA 58us -> MFMA-bound target.
// Schedule: barrier-bounded counted (safe class): per tile {vmcnt(2);
// barrier; loadB(t+1)->regs; GLDS A(t+2); ds_read af 4+4; 32 MFMA}.
// Ledger: steady outstanding = B(t)4+A(t+1)2; vm2 retires exactly B(t);
// A(t) retired one tile earlier; WAR: af(t-1) reads land before barrier(t)
// (lgkm before MFMA), so GLDS into buf[(t+2)%3] after barrier(t) is safe.
// XCD swizzle: each XCD owns 2 B-panels (4MB = its L2), sweeps 16 M-tiles.

#define M_DIM 4096
#define N_DIM 4096
#define K_DIM 4096

typedef __attribute__((ext_vector_type(8))) short short8;
typedef __attribute__((ext_vector_type(4))) float f32x4;

__device__ __forceinline__ unsigned short f2bf(float f) {
  uint32_t u = __builtin_bit_cast(uint32_t, f);
  u += 0x7fffu + ((u >> 16) & 1u);   // round-to-nearest-even
  return (unsigned short)(u >> 16);
}

// ---------- kernel 1a: x fp32 -> bf16 (ushort8 stores) ----------
__global__ __launch_bounds__(256) void cvt_kernel(const float* __restrict__ x,
                                                  unsigned short* __restrict__ xb) {
  const int tid = threadIdx.x;
  const int total = (M_DIM * K_DIM) / 8;   // 2M ushort8
  const float4* x4 = (const float4*)x;
  uint4* o8 = (uint4*)xb;
#pragma unroll
  for (int p = 0; p < 4; ++p) {
    int i = (p * 2048 + blockIdx.x) * 256 + tid;
    if (i < total) {
      float4 a = x4[2 * i], b = x4[2 * i + 1];
      uint4 o;
      o.x = (uint32_t)f2bf(a.x) | ((uint32_t)f2bf(a.y) << 16);
      o.y = (uint32_t)f2bf(a.z) | ((uint32_t)f2bf(a.w) << 16);
      o.z = (uint32_t)f2bf(b.x) | ((uint32_t)f2bf(b.y) << 16);
      o.w = (uint32_t)f2bf(b.z) | ((uint32_t)f2bf(b.w) << 16);
      o8[i] = o;
    }
  }
}

// ---------- kernel 1b: dequant -> fragment-major Wf ----------
// cell c (16B): lane = c&63, F = c>>6; t = F&127, nf = F>>7;
// fr = lane&15, fc = lane>>4; col n = nf*16+fr; gk = t*4+fc (8 k-elems).
// 2M cells = 2048 blocks x 256 threads x 4.
__global__ __launch_bounds__(256) void dequant_kernel(const int* __restrict__ Wq,
                                                      const float* __restrict__ scales,
                                                      const float* __restrict__ zeros,
                                                      uint4* __restrict__ wf) {
  const int tid = threadIdx.x;
#pragma unroll
  for (int p = 0; p < 4; ++p) {
    int c = (p * 2048 + blockIdx.x) * 256 + tid;
    int lane = c & 63;
    int F = c >> 6;
    int t = F & 127;
    int nf = F >> 7;
    int fr = lane & 15, fc = lane >> 4;
    int n = nf * 16 + fr;
    int gk = t * 4 + fc;
    int g = gk >> 4;
    uint32_t q = (uint32_t)Wq[gk * N_DIM + n];
    float s = scales[g * N_DIM + n];
    float z = zeros[g * N_DIM + n];
    unsigned short bb[8];
#pragma unroll
    for (int j = 0; j < 8; ++j) {
      float f = ((float)((q >> (4 * j)) & 15u) - z) * s;
      bb[j] = f2bf(f);
    }
    uint4 cell;
    cell.x = (uint32_t)bb[0] | ((uint32_t)bb[1] << 16);
    cell.y = (uint32_t)bb[2] | ((uint32_t)bb[3] << 16);
    cell.z = (uint32_t)bb[4] | ((uint32_t)bb[5] << 16);
    cell.w = (uint32_t)bb[6] | ((uint32_t)bb[7] << 16);
    wf[c] = cell;
  }
}

// ---------- kernel 2: bf16 GEMM, C = A @ W + bias ----------
// 256x256 tile, 8 waves (2Mx4N), per-wave 128x64 out = acc[8][4].
// A in LDS (3-ring of 256x32, XOR-cell: cell=row*4+(kc^((row>>1)&3)));
// B fragment-direct from L2 into bvP/bvQ ping-pong registers.

#define GLDS(DST, SRC)                                                          \
  __builtin_amdgcn_global_load_lds(                                             \
      (const __attribute__((address_space(1))) void*)(SRC),                     \
      (__attribute__((address_space(3))) void*)(DST), 16, 0, 0)

#define SB0 __builtin_amdgcn_sched_barrier(0)
#define VM2 asm volatile("s_waitcnt vmcnt(2)" ::: "memory")
#define VM0 asm volatile("s_waitcnt vmcnt(0)" ::: "memory")

// load 4 B-frags of tile T into DST regs (coalesced dwordx4 from L2)
#define LOADB(DST, T)                                                           \
  {                                                                             \
    _Pragma("unroll") for (int ni = 0; ni < 4; ++ni)                            \
        DST[ni] = __builtin_bit_cast(short8, Bf0[((size_t)ni * 128 + (T)) * 64]); \
  }

// one K-tile: wait+barrier, issue B(t+1)+A(t+2), read af 4+4, 32 MFMA
#define TILE(ACUR, AFAR, T, BVC, BVN, DO_LB, DO_SA, VMW)                        \
  {                                                                             \
    VMW;                                                                        \
    SB0;                                                                        \
    __builtin_amdgcn_s_barrier();                                               \
    SB0;                                                                        \
    if (DO_LB) LOADB(BVN, (T) + 1);                                             \
    if (DO_SA) {                                                                \
      const unsigned short* as_ = Asrc + (size_t)((T) + 2) * 32;                \
      GLDS((AFAR) + tid, as_);                                                  \
      GLDS((AFAR) + tid + 512, as_ + (size_t)128 * K_DIM);                      \
    }                                                                           \
    _Pragma("unroll") for (int mi = 0; mi < 4; ++mi) af[mi] = (ACUR)[a_b + mi * 64]; \
    __builtin_amdgcn_s_setprio(1);                                              \
    _Pragma("unroll") for (int mi = 0; mi < 4; ++mi)                            \
        _Pragma("unroll") for (int ni = 0; ni < 4; ++ni)                        \
            acc[mi][ni] = __builtin_amdgcn_mfma_f32_16x16x32_bf16(              \
                af[mi], BVC[ni], acc[mi][ni], 0, 0, 0);                         \
    __builtin_amdgcn_s_setprio(0);                                              \
    _Pragma("unroll") for (int mi = 0; mi < 4; ++mi) af[mi] = (ACUR)[a_b + (mi + 4) * 64]; \
    __builtin_amdgcn_s_setprio(1);                                              \
    _Pragma("unroll") for (int mi = 0; mi < 4; ++mi)                            \
        _Pragma("unroll") for (int ni = 0; ni < 4; ++ni)                        \
            acc[mi + 4][ni] = __builtin_amdgcn_mfma_f32_16x16x32_bf16(          \
                af[mi], BVC[ni], acc[mi + 4][ni], 0, 0, 0);                     \
    __builtin_amdgcn_s_setprio(0);                                              \
  }

#define ROT3 { short8* tmp_ = a0; a0 = a1; a1 = a2; a2 = tmp_; }

__global__ __launch_bounds__(512, 2) void gemm_bt_kernel(
    const unsigned short* __restrict__ A, const uint4* __restrict__ Wf,
    const float* __restrict__ bias, float* __restrict__ C) {
  __shared__ short8 As[3 * 1024];  // 48 KB: 3-ring of 256x32 bf16 (A only)

  const int tid = threadIdx.x;
  const int lane = tid & 63;
  const int w = tid >> 6;      // 0..7
  const int wm = w >> 2;       // 0..1
  const int wn = w & 3;        // 0..3

  // XCD swizzle: 256 blocks; xcd owns nt in {2*xcd, 2*xcd+1} (4MB of B = L2)
  const int b = blockIdx.x;
  const int xcd = b & 7;
  const int loc = b >> 3;              // 0..31
  const int nt = xcd * 2 + (loc & 1);  // 0..15
  const int mt = loc >> 1;             // 0..15
  const int m0 = mt * 256;
  const int n0 = nt * 256;

  // A staging: thread covers cells tid (rows 0..127) / tid+512 (rows 128..255)
  const int srow = tid >> 2;                        // 0..127
  const int skc = (tid & 3) ^ ((srow >> 1) & 3);    // swizzle inv under +128
  const unsigned short* Asrc = A + (size_t)(m0 + srow) * K_DIM + skc * 8;

  // B fragment-direct base: wave wn owns nf = n0/16 + wn*4 + ni
  const uint4* Bf0 = Wf + ((size_t)(n0 / 16 + wn * 4) * 128) * 64 + lane;

  // A fragment reads: rows wm*128 + mi*16 + fr, cell = row*4 + (fc^((row>>1)&3))
  const int fr = lane & 15;
  const int fc = lane >> 4;
  const int kxs = fc ^ ((fr >> 1) & 3);
  const int a_b = (wm * 128 + fr) * 4 + kxs;

  f32x4 acc[8][4] = {};
  short8 af[4];
  short8 bvP[4], bvQ[4];

  short8* a0 = As;
  short8* a1 = As + 1024;
  short8* a2 = As + 2048;

  // prologue (issue order = ledger order): A(0)x2, B(0)x4, A(1)x2
  GLDS(a0 + tid, Asrc);
  GLDS(a0 + tid + 512, Asrc + (size_t)128 * K_DIM);
  LOADB(bvP, 0);
  GLDS(a1 + tid, Asrc + 32);
  GLDS(a1 + tid + 512, Asrc + 32 + (size_t)128 * K_DIM);

  // main: tiles 0..125 full (stage A(t+2), load B(t+1))
  for (int t = 0; t < 126; t += 2) {
    TILE(a0, a2, t, bvP, bvQ, 1, 1, VM2);
    ROT3;
    TILE(a0, a2, t + 1, bvQ, bvP, 1, 1, VM2);
    ROT3;
  }
  // t=126: load B(127), no A stage
  TILE(a0, a2, 126, bvP, bvQ, 1, 0, VM2);
  ROT3;
  // t=127: drain
  TILE(a0, a2, 127, bvQ, bvP, 0, 0, VM0);

  // epilogue: C/D layout col=lane&15, row=(lane>>4)*4+reg
  const int rr = (lane >> 4) * 4;
#pragma unroll
  for (int ni = 0; ni < 4; ++ni) {
    const int gn = n0 + wn * 64 + ni * 16 + fr;
    const float bvv = bias[gn];
#pragma unroll
    for (int mi = 0; mi < 8; ++mi) {
      const int gm = m0 + wm * 128 + mi * 16 + rr;
#pragma unroll
      for (int r = 0; r < 4; ++r)
        C[(size_t)(gm + r) * N_DIM + gn] = acc[mi][ni][r] + bvv;
    }
  }
}

extern "C" void kernel_launch(void* const* d_in, const int* in_sizes, int n_in,
                              void* d_out, int out_size, void* d_ws, size_t ws_size,
                              hipStream_t stream) {
  const float* x = (const float*)d_in[0];
  const int* wq = (const int*)d_in[1];
  const float* sc = (const float*)d_in[2];
  const float* zr = (const float*)d_in[3];
  const float* bias = (const float*)d_in[4];
  float* out = (float*)d_out;

  unsigned short* xb = (unsigned short*)d_ws;
  uint4* wf = (uint4*)((char*)d_ws + (size_t)M_DIM * K_DIM * 2);

  cvt_kernel<<<dim3(2048), dim3(256), 0, stream>>>(x, xb);
  dequant_kernel<<<dim3(2048), dim3(256), 0, stream>>>(wq, sc, zr, wf);
  gemm_bt_kernel<<<dim3(256), dim3(512), 0, stream>>>(xb, wf, bias, out);
}